// Round 1
// baseline (184.596 us; speedup 1.0000x reference)
//
#include <hip/hip_runtime.h>

// ROI bilinear pooling, fp32.
// img: (B=16, H=64, W=64, C=512) NHWC fp32
// out: (B=16, R=16, P=7, P=7, C=512) fp32
// ROIs are compile-time constants: r -> y0=(r>>2)*16, x0=(r&3)*16, 16x16 crop.
// jax.image.resize(bilinear, antialias=False): pos = (i+0.5)*(16/7) - 0.5,
// always interior (0.643..14.357) => plain 2x2 tap, no clamping.

constexpr int C   = 512;
constexpr int W   = 64;
constexpr int H   = 64;
constexpr int P   = 7;
constexpr int C4  = C / 4;          // float4s per pixel = 128

__global__ __launch_bounds__(256) void roi_bilinear_kernel(
    const float* __restrict__ img, float* __restrict__ out)
{
    const int tid = blockIdx.x * blockDim.x + threadIdx.x;

    // tid -> (b, r, i, j, c4); c4 innermost for coalescing
    const int c4  = tid & (C4 - 1);
    int pix = tid >> 7;              // b*16*49 + r*49 + i*7 + j
    const int j = pix % P;
    pix /= P;
    const int i = pix % P;
    pix /= P;
    const int r = pix & 15;
    const int b = pix >> 4;

    // sample positions (half-pixel centers), 16 -> 7
    const float scale = 16.0f / 7.0f;
    const float py = (i + 0.5f) * scale - 0.5f;
    const float px = (j + 0.5f) * scale - 0.5f;
    const int   iy = (int)py;        // py,px > 0 always
    const int   jx = (int)px;
    const float fy = py - (float)iy;
    const float fx = px - (float)jx;

    const int y = (r >> 2) * 16 + iy;
    const int x = (r & 3)  * 16 + jx;

    const float4* p00 = (const float4*)(img) +
                        ((size_t)b * H + y) * W * C4 + (size_t)x * C4 + c4;
    const float4* p01 = p00 + C4;            // x+1
    const float4* p10 = p00 + (size_t)W * C4; // y+1
    const float4* p11 = p10 + C4;

    const float4 v00 = *p00;
    const float4 v01 = *p01;
    const float4 v10 = *p10;
    const float4 v11 = *p11;

    const float w00 = (1.0f - fy) * (1.0f - fx);
    const float w01 = (1.0f - fy) * fx;
    const float w10 = fy * (1.0f - fx);
    const float w11 = fy * fx;

    float4 o;
    o.x = w00 * v00.x + w01 * v01.x + w10 * v10.x + w11 * v11.x;
    o.y = w00 * v00.y + w01 * v01.y + w10 * v10.y + w11 * v11.y;
    o.z = w00 * v00.z + w01 * v01.z + w10 * v10.z + w11 * v11.z;
    o.w = w00 * v00.w + w01 * v01.w + w10 * v10.w + w11 * v11.w;

    ((float4*)out)[tid] = o;
}

extern "C" void kernel_launch(void* const* d_in, const int* in_sizes, int n_in,
                              void* d_out, int out_size, void* d_ws, size_t ws_size,
                              hipStream_t stream)
{
    const float* img = (const float*)d_in[0];
    float* out = (float*)d_out;

    // out_size = 16*16*7*7*512 = 6,422,528 floats = 1,605,632 float4s
    const int n_vec4 = out_size / 4;
    const int block  = 256;
    const int grid   = (n_vec4 + block - 1) / block;   // 6272

    roi_bilinear_kernel<<<grid, block, 0, stream>>>(img, out);
}

// Round 3
// 178.819 us; speedup vs baseline: 1.0323x; 1.0323x over previous
//
#include <hip/hip_runtime.h>

// ROI bilinear pooling, fp32.
// img: (B=16, H=64, W=64, C=512) NHWC fp32
// out: (B=16, R=16, P=7, P=7, C=512) fp32
// ROIs: r -> y0=(r>>2)*16, x0=(r&3)*16, 16x16 crop, resized 16->7 bilinear
// (half-pixel centers, antialias=False): pos=(i+0.5)*16/7-0.5, always interior.
//
// Traffic analysis: tap pairs (iy,iy+1) for i=0..6 are pairwise disjoint in
// both axes -> every used input pixel is read exactly once. Gross load =
// unique footprint = 98.3 MB; write = 25.7 MB; roofline ~20 us @ 6.3 TB/s.
// Both streams are touch-once -> nontemporal hints to avoid L2 pollution.

constexpr int C   = 512;
constexpr int W   = 64;
constexpr int H   = 64;
constexpr int P   = 7;
constexpr int C4  = C / 4;          // float4s per pixel = 128

// clang native vector type: legal operand for __builtin_nontemporal_*
typedef float f32x4 __attribute__((ext_vector_type(4)));

__global__ __launch_bounds__(256) void roi_bilinear_kernel(
    const float* __restrict__ img, float* __restrict__ out)
{
    const int tid = blockIdx.x * blockDim.x + threadIdx.x;

    // tid -> (b, r, i, j, c4); c4 innermost for coalescing
    const int c4  = tid & (C4 - 1);
    const int pix = tid >> 7;            // b*16*49 + r*49 + i*7 + j
    const int ij  = pix % 49;            // single division by 49
    const int br  = pix / 49;
    const int j   = ij % P;
    const int i   = ij / P;
    const int r   = br & 15;
    const int b   = br >> 4;

    // sample positions (half-pixel centers), 16 -> 7; always interior
    const float scale = 16.0f / 7.0f;
    const float py = (i + 0.5f) * scale - 0.5f;
    const float px = (j + 0.5f) * scale - 0.5f;
    const int   iy = (int)py;
    const int   jx = (int)px;
    const float fy = py - (float)iy;
    const float fx = px - (float)jx;

    const int y = (r >> 2) * 16 + iy;
    const int x = (r & 3)  * 16 + jx;

    const f32x4* p00 = (const f32x4*)(img) +
                       ((size_t)b * H + y) * W * C4 + (size_t)x * C4 + c4;
    const f32x4* p01 = p00 + C4;             // x+1
    const f32x4* p10 = p00 + (size_t)W * C4; // y+1
    const f32x4* p11 = p10 + C4;

    const f32x4 v00 = __builtin_nontemporal_load(p00);
    const f32x4 v01 = __builtin_nontemporal_load(p01);
    const f32x4 v10 = __builtin_nontemporal_load(p10);
    const f32x4 v11 = __builtin_nontemporal_load(p11);

    const float w00 = (1.0f - fy) * (1.0f - fx);
    const float w01 = (1.0f - fy) * fx;
    const float w10 = fy * (1.0f - fx);
    const float w11 = fy * fx;

    const f32x4 o = w00 * v00 + w01 * v01 + w10 * v10 + w11 * v11;

    __builtin_nontemporal_store(o, (f32x4*)out + tid);
}

extern "C" void kernel_launch(void* const* d_in, const int* in_sizes, int n_in,
                              void* d_out, int out_size, void* d_ws, size_t ws_size,
                              hipStream_t stream)
{
    const float* img = (const float*)d_in[0];
    float* out = (float*)d_out;

    // out_size = 16*16*7*7*512 = 6,422,528 floats = 1,605,632 float4s
    const int n_vec4 = out_size / 4;
    const int block  = 256;
    const int grid   = (n_vec4 + block - 1) / block;   // 6272

    roi_bilinear_kernel<<<grid, block, 0, stream>>>(img, out);
}